// Round 4
// baseline (653.352 us; speedup 1.0000x reference)
//
#include <hip/hip_runtime.h>

#define T_STEPS 512

typedef __attribute__((ext_vector_type(8))) short s16x8;  // 8 bf16 (4 VGPRs)
typedef __attribute__((ext_vector_type(4))) float f32x4;  // MFMA C/D

__device__ __forceinline__ short f2bf(float v) {          // fp32 -> bf16 RNE
    unsigned u = __float_as_uint(v);
    return (short)((u + 0x7FFFu + ((u >> 16) & 1u)) >> 16);
}
__device__ __forceinline__ float bf2f(short b) {
    return __uint_as_float(((unsigned)(unsigned short)b) << 16);
}
__device__ __forceinline__ float sigf(float x)  { return 1.f / (1.f + __expf(-x)); }
__device__ __forceinline__ float tanhf_(float x){ float e = __expf(2.f * x); return 1.f - 2.f / (e + 1.f); }

// Block: 2 batches, 512 threads = 8 waves; grid = B/2 = 512 -> 2 blocks/CU.
// Two INDEPENDENT barrier domains per CU: one block's MFMA/cell phases issue
// while the other waits at its barrier (the r3 kernel was latency/barrier
// bound with every pipe <40%).
// Wave w owns states 8w..8w+7 = two 16-row M-tiles per layer (14 MFMAs/wave).
// B fragments are M-invariant: read ONCE per wave, shared by both tiles ->
// per-CU LDS B-read traffic unchanged vs r3; only the MFMA pipe doubles.
// Phase 2: waves 0-1 = 128 L0 cells dense, waves 2-3 = 128 L1 cells dense,
// wave 4 stages x. B-read column clamp: only cols 0-1 are real batches;
// lanes n16>=2 broadcast col 1 (garbage only reaches D-cols 2-15, never read).
__global__ __launch_bounds__(512, 4)
void lstm2_mfma(const float* __restrict__ x,
                const float* __restrict__ Wih0, const float* __restrict__ Whh0,
                const float* __restrict__ bih0, const float* __restrict__ bhh0,
                const float* __restrict__ Wih1, const float* __restrict__ Whh1,
                const float* __restrict__ bih1, const float* __restrict__ bhh1,
                const float* __restrict__ Wfc,  const float* __restrict__ bfc,
                float* __restrict__ out)
{
    // B-operand buffers, bf16, [parity][n(2)][k] — only the 2 real columns.
    __shared__ __align__(16) short vinB[2][2][104];  // k: 0..31 x_t, 32..95 h0
    __shared__ __align__(16) short u1B [2][2][136];  // k: 0..63 h0, 64..127 h1
    // gate buffers: [state*2 + batch] -> f32x4 (i,f,g,o)
    __shared__ __align__(16) float gbuf0[128 * 4];   // L0 gates
    __shared__ __align__(16) float gbuf1[128 * 4];   // L1 gates

    const int tid  = threadIdx.x;
    const int w    = tid >> 6;       // wave 0..7
    const int lane = tid & 63;
    const int n16  = lane & 15;      // MFMA col (batch for n<2) / A-row m
    const int q4   = lane >> 4;      // quad: D-state-slot; A k-run
    const int b0   = blockIdx.x * 2;

    // ---- A fragments: two 16-row tiles per layer. Tile t row m -> gate m&3,
    //      state 8w + 4t + (m>>2). ----
    s16x8 a0[2], a1[2], a2[2];       // L0: K=96
    s16x8 e0[2], e1[2], e2[2], e3[2];// L1: K=128
    f32x4 bias0[2], bias1[2];
#pragma unroll
    for (int t = 0; t < 2; ++t) {
        const int rowW = (n16 & 3) * 64 + 8 * w + 4 * t + (n16 >> 2);
#pragma unroll
        for (int j = 0; j < 8; ++j) {
            a0[t][j] = f2bf(Wih0[rowW * 32 + q4 * 8 + j]);
            a1[t][j] = f2bf(Whh0[rowW * 64 + q4 * 8 + j]);
            a2[t][j] = f2bf(Whh0[rowW * 64 + 32 + q4 * 8 + j]);
            e0[t][j] = f2bf(Wih1[rowW * 64 + q4 * 8 + j]);
            e1[t][j] = f2bf(Wih1[rowW * 64 + 32 + q4 * 8 + j]);
            e2[t][j] = f2bf(Whh1[rowW * 64 + q4 * 8 + j]);
            e3[t][j] = f2bf(Whh1[rowW * 64 + 32 + q4 * 8 + j]);
        }
        const int jl = 8 * w + 4 * t + q4;   // state whose gates tile t's D row holds
#pragma unroll
        for (int p_ = 0; p_ < 4; ++p_) {
            bias0[t][p_] = bih0[p_ * 64 + jl] + bhh0[p_ * 64 + jl];
            bias1[t][p_] = bih1[p_ * 64 + jl] + bhh1[p_ * 64 + jl];
        }
    }

    // ---- gate-buffer indices ----
    const int gw0 = ((8 * w + q4) * 2 + n16) * 4;        // tile0 write (n16<2)
    const int gw1 = ((8 * w + 4 + q4) * 2 + n16) * 4;    // tile1 write
    const int cw2 = w & 1;                   // cell sub-wave (waves 0..3)
    const int cs  = 32 * cw2 + (lane >> 1);  // cell state 0..63
    const int cb  = lane & 1;                // cell batch 0..1
    const int gri = 64 * cw2 + lane;         // == cs*2 + cb

    // ---- B-read column clamp ----
    const int nB  = (n16 < 2) ? n16 : 1;

    // ---- x stager: wave 4 full-lane (64 = 2 batches x 32 k) ----
    const bool isx = (w == 4);
    const int  xb  = lane >> 5;              // 0..1
    const int  xk  = lane & 31;
    const float* xp = x + ((size_t)(b0 + xb) * T_STEPS) * 32 + xk;

    // ---- init: zero B-buffers; stage x_0 ----
    for (int i = tid; i < 2 * 2 * 104 / 2; i += 512) ((int*)vinB)[i] = 0;
    for (int i = tid; i < 2 * 2 * 136 / 2; i += 512) ((int*)u1B)[i]  = 0;
    __syncthreads();
    if (isx) vinB[0][xb][xk] = f2bf(xp[0]);
    __syncthreads();

    float cst0 = 0.f, cst1 = 0.f;    // fp32 cell states (waves 0-1 / 2-3)

    for (int it = 0; it <= T_STEPS; ++it) {
        const int p = it & 1;

        float xpre = 0.f;
        const bool havex = isx && (it + 1 < T_STEPS);
        if (havex) xpre = xp[(size_t)(it + 1) * 32];

        // ======== phase 1: gates via MFMA (all 8 waves) ========
        const short* vb = &vinB[p][nB][q4 * 8];
        s16x8 vb0 = *(const s16x8*)(vb);
        s16x8 vb1 = *(const s16x8*)(vb + 32);
        s16x8 vb2 = *(const s16x8*)(vb + 64);

        f32x4 d0a = __builtin_amdgcn_mfma_f32_16x16x32_bf16(a0[0], vb0, bias0[0], 0, 0, 0);
        f32x4 d0b = __builtin_amdgcn_mfma_f32_16x16x32_bf16(a0[1], vb0, bias0[1], 0, 0, 0);
        d0a = __builtin_amdgcn_mfma_f32_16x16x32_bf16(a1[0], vb1, d0a, 0, 0, 0);
        d0b = __builtin_amdgcn_mfma_f32_16x16x32_bf16(a1[1], vb1, d0b, 0, 0, 0);
        d0a = __builtin_amdgcn_mfma_f32_16x16x32_bf16(a2[0], vb2, d0a, 0, 0, 0);
        d0b = __builtin_amdgcn_mfma_f32_16x16x32_bf16(a2[1], vb2, d0b, 0, 0, 0);

        const short* ub = &u1B[p][nB][q4 * 8];
        s16x8 ub0 = *(const s16x8*)(ub);
        s16x8 ub1 = *(const s16x8*)(ub + 32);
        s16x8 ub2 = *(const s16x8*)(ub + 64);
        s16x8 ub3 = *(const s16x8*)(ub + 96);

        f32x4 d1a = __builtin_amdgcn_mfma_f32_16x16x32_bf16(e0[0], ub0, bias1[0], 0, 0, 0);
        f32x4 d1b = __builtin_amdgcn_mfma_f32_16x16x32_bf16(e0[1], ub0, bias1[1], 0, 0, 0);
        d1a = __builtin_amdgcn_mfma_f32_16x16x32_bf16(e1[0], ub1, d1a, 0, 0, 0);
        d1b = __builtin_amdgcn_mfma_f32_16x16x32_bf16(e1[1], ub1, d1b, 0, 0, 0);
        d1a = __builtin_amdgcn_mfma_f32_16x16x32_bf16(e2[0], ub2, d1a, 0, 0, 0);
        d1b = __builtin_amdgcn_mfma_f32_16x16x32_bf16(e2[1], ub2, d1b, 0, 0, 0);
        d1a = __builtin_amdgcn_mfma_f32_16x16x32_bf16(e3[0], ub3, d1a, 0, 0, 0);
        d1b = __builtin_amdgcn_mfma_f32_16x16x32_bf16(e3[1], ub3, d1b, 0, 0, 0);

        if (n16 < 2) {               // publish: 4 b128 writes, 8 lanes each,
                                     // 128 consecutive bytes -> conflict-free
            *(f32x4*)&gbuf0[gw0] = d0a;
            *(f32x4*)&gbuf0[gw1] = d0b;
            *(f32x4*)&gbuf1[gw0] = d1a;
            *(f32x4*)&gbuf1[gw1] = d1b;
        }
        __syncthreads();             // gates visible

        // ======== phase 2: dense cells (waves 0..3) + x stage (wave 4) ========
        if (w < 2) {
            if (it < T_STEPS) {      // L0 at step `it`: 128 cells, full-lane
                f32x4 g = *(const f32x4*)&gbuf0[gri * 4];
                float cc = sigf(g[1]) * cst0 + sigf(g[0]) * tanhf_(g[2]);
                cst0 = cc;
                short hb = f2bf(sigf(g[3]) * tanhf_(cc));
                vinB[p ^ 1][cb][32 + cs] = hb;   // L0's next input
                u1B [p ^ 1][cb][cs]      = hb;   // L1's input (k = cs)
            }
        } else if (w < 4) {
            if (it >= 1) {           // L1 at step `it-1`: 128 cells, full-lane
                f32x4 g = *(const f32x4*)&gbuf1[gri * 4];
                float cc = sigf(g[1]) * cst1 + sigf(g[0]) * tanhf_(g[2]);
                cst1 = cc;
                u1B[p ^ 1][cb][64 + cs] = f2bf(sigf(g[3]) * tanhf_(cc));
            }
        }
        if (havex) vinB[p ^ 1][xb][xk] = f2bf(xpre);
        __syncthreads();             // h + x visible for next step
    }

    // ---- final FC on h1[T-1] (last L1 write: it=512, p=0 -> u1B[1]) ----
    if (tid < 2) {
        float s = bfc[0];
#pragma unroll
        for (int k = 0; k < 64; ++k)
            s += bf2f(u1B[1][tid][64 + k]) * Wfc[k];
        out[b0 + tid] = s;
    }
}

extern "C" void kernel_launch(void* const* d_in, const int* in_sizes, int n_in,
                              void* d_out, int out_size, void* d_ws, size_t ws_size,
                              hipStream_t stream) {
    const float* x    = (const float*)d_in[0];
    const float* Wih0 = (const float*)d_in[1];
    const float* Whh0 = (const float*)d_in[2];
    const float* bih0 = (const float*)d_in[3];
    const float* bhh0 = (const float*)d_in[4];
    const float* Wih1 = (const float*)d_in[5];
    const float* Whh1 = (const float*)d_in[6];
    const float* bih1 = (const float*)d_in[7];
    const float* bhh1 = (const float*)d_in[8];
    const float* Wfc  = (const float*)d_in[9];
    const float* bfc  = (const float*)d_in[10];
    float* out = (float*)d_out;

    const int B = out_size;            // 1024
    dim3 grid(B / 2), block(512);      // 512 blocks -> 2 per CU
    hipLaunchKernelGGL(lstm2_mfma, grid, block, 0, stream,
                       x, Wih0, Whh0, bih0, bhh0,
                       Wih1, Whh1, bih1, bhh1, Wfc, bfc, out);
}

// Round 5
// 604.886 us; speedup vs baseline: 1.0801x; 1.0801x over previous
//
#include <hip/hip_runtime.h>

#define T_STEPS 512

typedef __attribute__((ext_vector_type(8))) short s16x8;  // 8 bf16 (4 VGPRs)
typedef __attribute__((ext_vector_type(4))) float f32x4;  // MFMA C/D

__device__ __forceinline__ short f2bf(float v) {          // fp32 -> bf16 RNE
    unsigned u = __float_as_uint(v);
    return (short)((u + 0x7FFFu + ((u >> 16) & 1u)) >> 16);
}
__device__ __forceinline__ float bf2f(short b) {
    return __uint_as_float(((unsigned)(unsigned short)b) << 16);
}
__device__ __forceinline__ float sigf(float x)  { return 1.f / (1.f + __expf(-x)); }
__device__ __forceinline__ float tanhf_(float x){ float e = __expf(2.f * x); return 1.f - 2.f / (e + 1.f); }

// Block: 2 batches, 512 threads = 8 waves; grid = 512 -> 2 blocks/CU (two
// independent barrier domains overlap each other's stalls).
// r4 failed on SPILL (compiler chose 64 VGPR for 8 waves/EU, 40MB scratch).
// Fixes here:
//  (a) amdgpu_waves_per_eu(4,4): pin occupancy target -> 128-VGPR budget.
//  (b) merged B buffer [x(32)|h0(64)|h1(64)]: h0 was stored/read TWICE
//      (vinB k32..95 == u1B k0..63). Now 5 B-frag reads/wave (was 7),
//      h0 written once -> -24 VGPRs demand, -29% LDS-read traffic.
//  (c) bias moved from MFMA C-seed to cell phase (+4 VALU adds there),
//      -16 invariant VGPRs.
// Wave w owns states 8w..8w+7 (two 16-row M-tiles/layer, 14 MFMAs). B frags
// M-invariant: read once, feed both tiles. Phase 2: waves 0-1 = 128 L0 cells
// dense, 2-3 = 128 L1 cells, wave 4 stages x. B-col clamp: cols 0-1 real,
// lanes n16>=2 broadcast col 1 (garbage only in D-cols 2-15, never read).
__global__ __launch_bounds__(512) __attribute__((amdgpu_waves_per_eu(4, 4)))
void lstm2_mfma(const float* __restrict__ x,
                const float* __restrict__ Wih0, const float* __restrict__ Whh0,
                const float* __restrict__ bih0, const float* __restrict__ bhh0,
                const float* __restrict__ Wih1, const float* __restrict__ Whh1,
                const float* __restrict__ bih1, const float* __restrict__ bhh1,
                const float* __restrict__ Wfc,  const float* __restrict__ bfc,
                float* __restrict__ out)
{
    // merged B buffer, bf16, [parity][n(2)][k]: x 0..31 | h0 32..95 | h1 96..159
    // stride 168 shorts = 336 B; col1 dword offset 84 % 32 = 20 -> 2-way max (free)
    __shared__ __align__(16) short bB[2][2][168];
    // gate buffers: [state*2 + batch] -> f32x4 (i,f,g,o), bias NOT included
    __shared__ __align__(16) float gbuf0[128 * 4];   // L0
    __shared__ __align__(16) float gbuf1[128 * 4];   // L1

    const int tid  = threadIdx.x;
    const int w    = tid >> 6;       // wave 0..7
    const int lane = tid & 63;
    const int n16  = lane & 15;      // MFMA col (batch for n<2) / A-row m
    const int q4   = lane >> 4;      // quad: D-state-slot; A k-run
    const int b0   = blockIdx.x * 2;

    // ---- A fragments: two 16-row tiles per layer. Tile t row m -> gate m&3,
    //      state 8w + 4t + (m>>2). ----
    s16x8 a0[2], a1[2], a2[2];       // L0: K=96  {x, h0_lo, h0_hi}
    s16x8 e0[2], e1[2], e2[2], e3[2];// L1: K=128 {h0_lo, h0_hi, h1_lo, h1_hi}
#pragma unroll
    for (int t = 0; t < 2; ++t) {
        const int rowW = (n16 & 3) * 64 + 8 * w + 4 * t + (n16 >> 2);
#pragma unroll
        for (int j = 0; j < 8; ++j) {
            a0[t][j] = f2bf(Wih0[rowW * 32 + q4 * 8 + j]);
            a1[t][j] = f2bf(Whh0[rowW * 64 + q4 * 8 + j]);
            a2[t][j] = f2bf(Whh0[rowW * 64 + 32 + q4 * 8 + j]);
            e0[t][j] = f2bf(Wih1[rowW * 64 + q4 * 8 + j]);
            e1[t][j] = f2bf(Wih1[rowW * 64 + 32 + q4 * 8 + j]);
            e2[t][j] = f2bf(Whh1[rowW * 64 + q4 * 8 + j]);
            e3[t][j] = f2bf(Whh1[rowW * 64 + 32 + q4 * 8 + j]);
        }
    }

    // ---- gate-buffer indices ----
    const int gw0 = ((8 * w + q4) * 2 + n16) * 4;        // tile0 write (n16<2)
    const int gw1 = ((8 * w + 4 + q4) * 2 + n16) * 4;    // tile1 write
    const int cw2 = w & 1;                   // cell sub-wave (waves 0..3)
    const int cs  = 32 * cw2 + (lane >> 1);  // cell state 0..63
    const int cb  = lane & 1;                // cell batch 0..1
    const int gri = 64 * cw2 + lane;         // == cs*2 + cb

    // ---- per-cell bias (gate p of state cs), cell waves only use it ----
    const float* bi = (w >= 2) ? bih1 : bih0;
    const float* bh = (w >= 2) ? bhh1 : bhh0;
    f32x4 bC;
#pragma unroll
    for (int p_ = 0; p_ < 4; ++p_) bC[p_] = bi[p_ * 64 + cs] + bh[p_ * 64 + cs];

    // ---- B-read column clamp ----
    const int nB  = (n16 < 2) ? n16 : 1;

    // ---- x stager: wave 4 full-lane (64 = 2 batches x 32 k) ----
    const bool isx = (w == 4);
    const int  xb  = lane >> 5;              // 0..1
    const int  xk  = lane & 31;
    const float* xp = x + ((size_t)(b0 + xb) * T_STEPS) * 32 + xk;

    // ---- init: zero B buffer; stage x_0 ----
    for (int i = tid; i < 2 * 2 * 168 / 2; i += 512) ((int*)bB)[i] = 0;
    __syncthreads();
    if (isx) bB[0][xb][xk] = f2bf(xp[0]);
    __syncthreads();

    float cst0 = 0.f, cst1 = 0.f;    // fp32 cell states (waves 0-1 / 2-3)
    const f32x4 zz = {0.f, 0.f, 0.f, 0.f};

    for (int it = 0; it <= T_STEPS; ++it) {
        const int p = it & 1;

        float xpre = 0.f;
        const bool havex = isx && (it + 1 < T_STEPS);
        if (havex) xpre = xp[(size_t)(it + 1) * 32];

        // ======== phase 1: gates via MFMA (all 8 waves), 5 B-frag reads ========
        const short* bp = &bB[p][nB][q4 * 8];
        s16x8 t0 = *(const s16x8*)(bp);          // x[it]
        s16x8 t1 = *(const s16x8*)(bp + 32);     // h0 lo
        s16x8 t2 = *(const s16x8*)(bp + 64);     // h0 hi
        s16x8 t3 = *(const s16x8*)(bp + 96);     // h1 lo
        s16x8 t4 = *(const s16x8*)(bp + 128);    // h1 hi

        f32x4 d0a = __builtin_amdgcn_mfma_f32_16x16x32_bf16(a0[0], t0, zz, 0, 0, 0);
        f32x4 d0b = __builtin_amdgcn_mfma_f32_16x16x32_bf16(a0[1], t0, zz, 0, 0, 0);
        d0a = __builtin_amdgcn_mfma_f32_16x16x32_bf16(a1[0], t1, d0a, 0, 0, 0);
        d0b = __builtin_amdgcn_mfma_f32_16x16x32_bf16(a1[1], t1, d0b, 0, 0, 0);
        d0a = __builtin_amdgcn_mfma_f32_16x16x32_bf16(a2[0], t2, d0a, 0, 0, 0);
        d0b = __builtin_amdgcn_mfma_f32_16x16x32_bf16(a2[1], t2, d0b, 0, 0, 0);

        f32x4 d1a = __builtin_amdgcn_mfma_f32_16x16x32_bf16(e0[0], t1, zz, 0, 0, 0);
        f32x4 d1b = __builtin_amdgcn_mfma_f32_16x16x32_bf16(e0[1], t1, zz, 0, 0, 0);
        d1a = __builtin_amdgcn_mfma_f32_16x16x32_bf16(e1[0], t2, d1a, 0, 0, 0);
        d1b = __builtin_amdgcn_mfma_f32_16x16x32_bf16(e1[1], t2, d1b, 0, 0, 0);
        d1a = __builtin_amdgcn_mfma_f32_16x16x32_bf16(e2[0], t3, d1a, 0, 0, 0);
        d1b = __builtin_amdgcn_mfma_f32_16x16x32_bf16(e2[1], t3, d1b, 0, 0, 0);
        d1a = __builtin_amdgcn_mfma_f32_16x16x32_bf16(e3[0], t4, d1a, 0, 0, 0);
        d1b = __builtin_amdgcn_mfma_f32_16x16x32_bf16(e3[1], t4, d1b, 0, 0, 0);

        if (n16 < 2) {               // publish gate vectors (conflict-free b128)
            *(f32x4*)&gbuf0[gw0] = d0a;
            *(f32x4*)&gbuf0[gw1] = d0b;
            *(f32x4*)&gbuf1[gw0] = d1a;
            *(f32x4*)&gbuf1[gw1] = d1b;
        }
        __syncthreads();             // gates visible

        // ======== phase 2: dense cells (waves 0..3) + x stage (wave 4) ========
        if (w < 2) {
            if (it < T_STEPS) {      // L0 at step `it`: 128 cells, full-lane
                f32x4 g = *(const f32x4*)&gbuf0[gri * 4];
                float cc = sigf(g[1] + bC[1]) * cst0
                         + sigf(g[0] + bC[0]) * tanhf_(g[2] + bC[2]);
                cst0 = cc;
                bB[p ^ 1][cb][32 + cs] = f2bf(sigf(g[3] + bC[3]) * tanhf_(cc));
            }
        } else if (w < 4) {
            if (it >= 1) {           // L1 at step `it-1`: 128 cells, full-lane
                f32x4 g = *(const f32x4*)&gbuf1[gri * 4];
                float cc = sigf(g[1] + bC[1]) * cst1
                         + sigf(g[0] + bC[0]) * tanhf_(g[2] + bC[2]);
                cst1 = cc;
                bB[p ^ 1][cb][96 + cs] = f2bf(sigf(g[3] + bC[3]) * tanhf_(cc));
            }
        }
        if (havex) bB[p ^ 1][xb][xk] = f2bf(xpre);
        __syncthreads();             // h + x visible for next step
    }

    // ---- final FC on h1[T-1] (last L1 write: it=512, p=0 -> bB[1]) ----
    if (tid < 2) {
        float s = bfc[0];
#pragma unroll
        for (int k = 0; k < 64; ++k)
            s += bf2f(bB[1][tid][96 + k]) * Wfc[k];
        out[b0 + tid] = s;
    }
}

extern "C" void kernel_launch(void* const* d_in, const int* in_sizes, int n_in,
                              void* d_out, int out_size, void* d_ws, size_t ws_size,
                              hipStream_t stream) {
    const float* x    = (const float*)d_in[0];
    const float* Wih0 = (const float*)d_in[1];
    const float* Whh0 = (const float*)d_in[2];
    const float* bih0 = (const float*)d_in[3];
    const float* bhh0 = (const float*)d_in[4];
    const float* Wih1 = (const float*)d_in[5];
    const float* Whh1 = (const float*)d_in[6];
    const float* bih1 = (const float*)d_in[7];
    const float* bhh1 = (const float*)d_in[8];
    const float* Wfc  = (const float*)d_in[9];
    const float* bfc  = (const float*)d_in[10];
    float* out = (float*)d_out;

    const int B = out_size;            // 1024
    dim3 grid(B / 2), block(512);      // 512 blocks -> 2 per CU
    hipLaunchKernelGGL(lstm2_mfma, grid, block, 0, stream,
                       x, Wih0, Whh0, bih0, bhh0,
                       Wih1, Whh1, bih1, bhh1, Wfc, bfc, out);
}

// Round 6
// 581.005 us; speedup vs baseline: 1.1245x; 1.0411x over previous
//
#include <hip/hip_runtime.h>

#define T_STEPS 512

typedef __attribute__((ext_vector_type(8))) short s16x8;  // 8 bf16 (4 VGPRs)
typedef __attribute__((ext_vector_type(4))) float f32x4;  // MFMA C/D

__device__ __forceinline__ short f2bf(float v) {          // fp32 -> bf16 RNE
    unsigned u = __float_as_uint(v);
    return (short)((u + 0x7FFFu + ((u >> 16) & 1u)) >> 16);
}
__device__ __forceinline__ float bf2f(short b) {
    return __uint_as_float(((unsigned)(unsigned short)b) << 16);
}
__device__ __forceinline__ float sigf(float x)  { return 1.f / (1.f + __expf(-x)); }
__device__ __forceinline__ float tanhf_(float x){ float e = __expf(2.f * x); return 1.f - 2.f / (e + 1.f); }

// Block: 4 batches, 512 threads = 8 waves; grid = 256 -> 1 block/CU.
// r3 analysis: LDS instruction pipe (~12 cyc/wave64 b128 op) was ~77% of the
// step. This version halves per-CU LDS ops (164 -> ~90): 8 waves x 14 MFMAs
// (M=32/layer each; B frags M-invariant -> read ONCE, feed both tiles), so
// B-reads are 40/step instead of 80/112. Register demand ~130 fits the
// 256-reg unified cap from __launch_bounds__(512, 2) -> no spill (r4/r5
// lesson: the 2nd arg caps TOTAL unified regs at 512/min_waves).
// Phase 2: ALL 8 waves dense-cell (0-3 = 256 L0 cells, 4-7 = 256 L1 cells);
// waves 0-1 also stage x (prefetched at loop top).
// B-col clamp: cols 0-3 real; lanes n16>=4 broadcast col 3 (garbage only in
// D-cols 4-15, never read). bB stride 176 shorts -> B-read bases land exactly
// 2 requests/bank = wave64 floor (conflict-free).
__global__ __launch_bounds__(512, 2)
void lstm2_mfma(const float* __restrict__ x,
                const float* __restrict__ Wih0, const float* __restrict__ Whh0,
                const float* __restrict__ bih0, const float* __restrict__ bhh0,
                const float* __restrict__ Wih1, const float* __restrict__ Whh1,
                const float* __restrict__ bih1, const float* __restrict__ bhh1,
                const float* __restrict__ Wfc,  const float* __restrict__ bfc,
                float* __restrict__ out)
{
    // merged B buffer, bf16, [parity][n(4)][k]: x 0..31 | h0 32..95 | h1 96..159
    __shared__ __align__(16) short bB[2][4][176];
    // gate buffers: [state*4 + batch] -> f32x4 (i,f,g,o), bias included (C-seed)
    __shared__ __align__(16) float gbuf0[256 * 4];   // L0
    __shared__ __align__(16) float gbuf1[256 * 4];   // L1

    const int tid  = threadIdx.x;
    const int w    = tid >> 6;       // wave 0..7
    const int lane = tid & 63;
    const int n16  = lane & 15;      // MFMA col (batch for n<4) / A-row m
    const int q4   = lane >> 4;      // quad: D-state-slot; A k-run
    const int b0   = blockIdx.x * 4;

    // ---- A fragments: two 16-row tiles per layer. Tile t row m -> gate m&3,
    //      state 8w + 4t + (m>>2). ----
    s16x8 a0[2], a1[2], a2[2];       // L0: K=96  {x, h0_lo, h0_hi}
    s16x8 e0[2], e1[2], e2[2], e3[2];// L1: K=128 {h0_lo, h0_hi, h1_lo, h1_hi}
    f32x4 bias0[2], bias1[2];
#pragma unroll
    for (int t = 0; t < 2; ++t) {
        const int rowW = (n16 & 3) * 64 + 8 * w + 4 * t + (n16 >> 2);
#pragma unroll
        for (int j = 0; j < 8; ++j) {
            a0[t][j] = f2bf(Wih0[rowW * 32 + q4 * 8 + j]);
            a1[t][j] = f2bf(Whh0[rowW * 64 + q4 * 8 + j]);
            a2[t][j] = f2bf(Whh0[rowW * 64 + 32 + q4 * 8 + j]);
            e0[t][j] = f2bf(Wih1[rowW * 64 + q4 * 8 + j]);
            e1[t][j] = f2bf(Wih1[rowW * 64 + 32 + q4 * 8 + j]);
            e2[t][j] = f2bf(Whh1[rowW * 64 + q4 * 8 + j]);
            e3[t][j] = f2bf(Whh1[rowW * 64 + 32 + q4 * 8 + j]);
        }
        const int jl = 8 * w + 4 * t + q4;   // state whose gates tile t's D holds
#pragma unroll
        for (int p_ = 0; p_ < 4; ++p_) {
            bias0[t][p_] = bih0[p_ * 64 + jl] + bhh0[p_ * 64 + jl];
            bias1[t][p_] = bih1[p_ * 64 + jl] + bhh1[p_ * 64 + jl];
        }
    }

    // ---- gate-buffer indices (writes: lanes n16<4) ----
    const int gw0 = ((8 * w + q4) * 4 + n16) * 4;        // tile0
    const int gw1 = ((8 * w + 4 + q4) * 4 + n16) * 4;    // tile1
    const int cw  = w & 3;                   // cell sub-wave id within layer group
    const int cs  = 16 * cw + (lane >> 2);   // cell state 0..63
    const int cb  = lane & 3;                // cell batch 0..3
    const int gri = 64 * cw + lane;          // == cs*4 + cb (consecutive b128)

    // ---- B-read column clamp ----
    const int nB  = (n16 < 4) ? n16 : 3;

    // ---- x stagers: waves 0-1 (also cell waves; load prefetched early).
    //      wave w stages batches 2w, 2w+1; full-lane: 2 batches x 32 k. ----
    const bool isx = (w < 2);
    const int  xb  = w * 2 + (lane >> 5);    // 0..3
    const int  xk  = lane & 31;
    const float* xp = x + ((size_t)(b0 + xb) * T_STEPS) * 32 + xk;

    // ---- init: zero B buffer; stage x_0 ----
    for (int i = tid; i < 2 * 4 * 176 / 2; i += 512) ((int*)bB)[i] = 0;
    __syncthreads();
    if (isx) bB[0][xb][xk] = f2bf(xp[0]);
    __syncthreads();

    float cst0 = 0.f, cst1 = 0.f;    // fp32 cell states (waves 0-3 / 4-7)

    for (int it = 0; it <= T_STEPS; ++it) {
        const int p = it & 1;

        float xpre = 0.f;
        const bool havex = isx && (it + 1 < T_STEPS);
        if (havex) xpre = xp[(size_t)(it + 1) * 32];   // ~2 phases ahead of use

        // ======== phase 1: gates via MFMA (all 8 waves), 5 B-frag reads ========
        const short* bp = &bB[p][nB][q4 * 8];
        s16x8 t0 = *(const s16x8*)(bp);          // x[it]
        s16x8 t1 = *(const s16x8*)(bp + 32);     // h0 lo
        s16x8 t2 = *(const s16x8*)(bp + 64);     // h0 hi
        s16x8 t3 = *(const s16x8*)(bp + 96);     // h1 lo
        s16x8 t4 = *(const s16x8*)(bp + 128);    // h1 hi

        f32x4 d0a = __builtin_amdgcn_mfma_f32_16x16x32_bf16(a0[0], t0, bias0[0], 0, 0, 0);
        f32x4 d0b = __builtin_amdgcn_mfma_f32_16x16x32_bf16(a0[1], t0, bias0[1], 0, 0, 0);
        d0a = __builtin_amdgcn_mfma_f32_16x16x32_bf16(a1[0], t1, d0a, 0, 0, 0);
        d0b = __builtin_amdgcn_mfma_f32_16x16x32_bf16(a1[1], t1, d0b, 0, 0, 0);
        d0a = __builtin_amdgcn_mfma_f32_16x16x32_bf16(a2[0], t2, d0a, 0, 0, 0);
        d0b = __builtin_amdgcn_mfma_f32_16x16x32_bf16(a2[1], t2, d0b, 0, 0, 0);

        f32x4 d1a = __builtin_amdgcn_mfma_f32_16x16x32_bf16(e0[0], t1, bias1[0], 0, 0, 0);
        f32x4 d1b = __builtin_amdgcn_mfma_f32_16x16x32_bf16(e0[1], t1, bias1[1], 0, 0, 0);
        d1a = __builtin_amdgcn_mfma_f32_16x16x32_bf16(e1[0], t2, d1a, 0, 0, 0);
        d1b = __builtin_amdgcn_mfma_f32_16x16x32_bf16(e1[1], t2, d1b, 0, 0, 0);
        d1a = __builtin_amdgcn_mfma_f32_16x16x32_bf16(e2[0], t3, d1a, 0, 0, 0);
        d1b = __builtin_amdgcn_mfma_f32_16x16x32_bf16(e2[1], t3, d1b, 0, 0, 0);
        d1a = __builtin_amdgcn_mfma_f32_16x16x32_bf16(e3[0], t4, d1a, 0, 0, 0);
        d1b = __builtin_amdgcn_mfma_f32_16x16x32_bf16(e3[1], t4, d1b, 0, 0, 0);

        if (n16 < 4) {               // publish gates: 4 b128 writes, 2-way (free)
            *(f32x4*)&gbuf0[gw0] = d0a;
            *(f32x4*)&gbuf0[gw1] = d0b;
            *(f32x4*)&gbuf1[gw0] = d1a;
            *(f32x4*)&gbuf1[gw1] = d1b;
        }
        __syncthreads();             // gates visible

        // ======== phase 2: ALL waves dense cells; waves 0-1 also stage x ========
        if (w < 4) {
            if (it < T_STEPS) {      // L0 at step `it`: 256 cells, full-lane
                f32x4 g = *(const f32x4*)&gbuf0[gri * 4];
                float cc = sigf(g[1]) * cst0 + sigf(g[0]) * tanhf_(g[2]);
                cst0 = cc;
                bB[p ^ 1][cb][32 + cs] = f2bf(sigf(g[3]) * tanhf_(cc));
            }
        } else {
            if (it >= 1) {           // L1 at step `it-1`: 256 cells, full-lane
                f32x4 g = *(const f32x4*)&gbuf1[gri * 4];
                float cc = sigf(g[1]) * cst1 + sigf(g[0]) * tanhf_(g[2]);
                cst1 = cc;
                bB[p ^ 1][cb][96 + cs] = f2bf(sigf(g[3]) * tanhf_(cc));
            }
        }
        if (havex) bB[p ^ 1][xb][xk] = f2bf(xpre);
        __syncthreads();             // h + x visible for next step
    }

    // ---- final FC on h1[T-1] (last L1 write: it=512, p=0 -> bB[1]) ----
    if (tid < 4) {
        float s = bfc[0];
#pragma unroll
        for (int k = 0; k < 64; ++k)
            s += bf2f(bB[1][tid][96 + k]) * Wfc[k];
        out[b0 + tid] = s;
    }
}

extern "C" void kernel_launch(void* const* d_in, const int* in_sizes, int n_in,
                              void* d_out, int out_size, void* d_ws, size_t ws_size,
                              hipStream_t stream) {
    const float* x    = (const float*)d_in[0];
    const float* Wih0 = (const float*)d_in[1];
    const float* Whh0 = (const float*)d_in[2];
    const float* bih0 = (const float*)d_in[3];
    const float* bhh0 = (const float*)d_in[4];
    const float* Wih1 = (const float*)d_in[5];
    const float* Whh1 = (const float*)d_in[6];
    const float* bih1 = (const float*)d_in[7];
    const float* bhh1 = (const float*)d_in[8];
    const float* Wfc  = (const float*)d_in[9];
    const float* bfc  = (const float*)d_in[10];
    float* out = (float*)d_out;

    const int B = out_size;            // 1024
    dim3 grid(B / 4), block(512);      // 256 blocks -> 1 per CU
    hipLaunchKernelGGL(lstm2_mfma, grid, block, 0, stream,
                       x, Wih0, Whh0, bih0, bhh0,
                       Wih1, Whh1, bih1, bhh1, Wfc, bfc, out);
}